// Round 3
// baseline (106.972 us; speedup 1.0000x reference)
//
#include <hip/hip_runtime.h>

#define GRID_N 192
constexpr int NROWS = GRID_N * GRID_N;    // 36864 rows of 192 floats (h contiguous)
constexpr int RPB   = 48;                 // rows per block; block = one l, 48 consecutive w
constexpr int NBLK  = NROWS / RPB;        // 768
constexpr int RPW   = RPB / 4;            // 12 rows per wave

// --- Path A: unique per-block partial records in ws (no atomics) ---
// record (floats): [0..383]  (hD,hM) pairs per h (192 pairs)
//                  [384..479] (wD,wM) pairs per local w (48 pairs)
//                  [480..481] (lD,lM)
constexpr int PSTRIDE = 512;              // floats per record (padded)
constexpr size_t STAGE_BYTES = (size_t)NBLK * PSTRIDE * sizeof(float); // 1.57 MB

// --- Path B fallback: replicated atomic accumulator (R2 scheme) ---
constexpr int ACC_FLOATS = 1152;

__global__ __launch_bounds__(256) void slice_stage1(
    const float* __restrict__ vx,  const float* __restrict__ vy,
    const float* __restrict__ vz,  const float* __restrict__ p,
    const float* __restrict__ mask,
    const float* __restrict__ rvx, const float* __restrict__ rvy,
    const float* __restrict__ rvz, const float* __restrict__ rp,
    float* __restrict__ part)
{
    const int tid  = threadIdx.x;
    const int wv   = tid >> 6;
    const int lane = tid & 63;
    const bool act = lane < 48;           // 48 lanes x float4 = one 192-float row
    const int hb   = lane << 2;

    const int l  = blockIdx.x >> 2;
    const int w0 = (blockIdx.x & 3) * RPB;
    const int rowbase = l * GRID_N + w0 + wv * RPW;
    float* __restrict__ rec = part + (size_t)blockIdx.x * PSTRIDE;

    __shared__ float sD[4][192];
    __shared__ float sM[4][192];
    __shared__ float sRowD[RPB][49];      // [local w][lane], padded stride
    __shared__ float sRowM[RPB][49];
    __shared__ float sL[2][4];

    float cD0=0.f,cD1=0.f,cD2=0.f,cD3=0.f;
    float cM0=0.f,cM1=0.f,cM2=0.f,cM3=0.f;

#pragma unroll 4
    for (int r = 0; r < RPW; ++r) {
        const int row = rowbase + r;
        float d0=0.f,d1=0.f,d2=0.f,d3=0.f;
        float m0=0.f,m1=0.f,m2=0.f,m3=0.f;
        if (act) {
            const size_t base = (size_t)row * GRID_N + hb;
            float4 a, b;
            a = *(const float4*)(rvx + base); b = *(const float4*)(vx + base);
            d0 = a.x-b.x; d1 = a.y-b.y; d2 = a.z-b.z; d3 = a.w-b.w;
            a = *(const float4*)(rvy + base); b = *(const float4*)(vy + base);
            d0 += a.x-b.x; d1 += a.y-b.y; d2 += a.z-b.z; d3 += a.w-b.w;
            a = *(const float4*)(rvz + base); b = *(const float4*)(vz + base);
            d0 += a.x-b.x; d1 += a.y-b.y; d2 += a.z-b.z; d3 += a.w-b.w;
            a = *(const float4*)(rp  + base); b = *(const float4*)(p  + base);
            d0 += a.x-b.x; d1 += a.y-b.y; d2 += a.z-b.z; d3 += a.w-b.w;
            a = *(const float4*)(mask + base);
            m0 = a.x; m1 = a.y; m2 = a.z; m3 = a.w;
        }
        cD0 += d0; cD1 += d1; cD2 += d2; cD3 += d3;
        cM0 += m0; cM1 += m1; cM2 += m2; cM3 += m3;
        if (act) {
            // fire-and-forget row scalar; no cross-lane chain
            sRowD[wv * RPW + r][lane] = (d0 + d1) + (d2 + d3);
            sRowM[wv * RPW + r][lane] = (m0 + m1) + (m2 + m3);
        }
    }

    if (act) {
        sD[wv][hb+0]=cD0; sD[wv][hb+1]=cD1; sD[wv][hb+2]=cD2; sD[wv][hb+3]=cD3;
        sM[wv][hb+0]=cM0; sM[wv][hb+1]=cM1; sM[wv][hb+2]=cM2; sM[wv][hb+3]=cM3;
    }
    __syncthreads();

    // h columns: combine 4 waves, write (hD,hM) pair per h
    float d = 0.f, m = 0.f;
    if (tid < 192) {
        d = (sD[0][tid] + sD[1][tid]) + (sD[2][tid] + sD[3][tid]);
        m = (sM[0][tid] + sM[1][tid]) + (sM[2][tid] + sM[3][tid]);
        rec[2*tid]     = d;
        rec[2*tid + 1] = m;
    }
    // w slots: reduce sRow[w][0..47]
    if (tid < RPB) {
        float wd = 0.f, wm = 0.f;
#pragma unroll 8
        for (int i = 0; i < 48; ++i) {
            wd += sRowD[tid][i];
            wm += sRowM[tid][i];
        }
        rec[384 + 2*tid]     = wd;
        rec[384 + 2*tid + 1] = wm;
    }
    // l partial = sum of this block's h-column totals (plane partial)
    {
        float td = d, tm = m;   // zeros for tid>=192
#pragma unroll
        for (int off = 32; off; off >>= 1) {
            td += __shfl_xor(td, off);
            tm += __shfl_xor(tm, off);
        }
        if (lane == 0) { sL[0][wv] = td; sL[1][wv] = tm; }
    }
    __syncthreads();
    if (tid == 0) {
        rec[480] = (sL[0][0] + sL[0][1]) + (sL[0][2] + sL[0][3]);
        rec[481] = (sL[1][0] + sL[1][1]) + (sL[1][2] + sL[1][3]);
    }
}

__global__ __launch_bounds__(768) void slice_stage2(
    const float* __restrict__ part, float* __restrict__ out)
{
    const int tid = threadIdx.x;
    const int t = tid % 192;   // slice index
    const int pg = tid / 192;  // 0..3 partition group

    float hD=0.f, hM=0.f, wD=0.f, wM=0.f, lD=0.f, lM=0.f;
    // h: all 768 blocks contribute; split 4 ways
    for (int b = pg; b < NBLK; b += 4) {
        float2 v = *(const float2*)(part + (size_t)b * PSTRIDE + 2*t);
        hD += v.x; hM += v.y;
    }
    // w: blocks b = l*4 + q, q = t/48, local w = t%48; split l 4 ways
    {
        const int q = t / 48, lw = t % 48;
        for (int li = pg; li < GRID_N; li += 4) {
            float2 v = *(const float2*)(part + (size_t)(li*4 + q) * PSTRIDE + 384 + 2*lw);
            wD += v.x; wM += v.y;
        }
    }
    // l: blocks b = t*4 + q; this group takes q = pg
    {
        float2 v = *(const float2*)(part + (size_t)(t*4 + pg) * PSTRIDE + 480);
        lD = v.x; lM = v.y;
    }

    __shared__ float sh[6][4][192];
    sh[0][pg][t]=hD; sh[1][pg][t]=hM; sh[2][pg][t]=wD;
    sh[3][pg][t]=wM; sh[4][pg][t]=lD; sh[5][pg][t]=lM;
    __syncthreads();

    __shared__ double sdbl[3];
    if (tid < 192) {
        double HD=0,HM=0,WD=0,WM=0,LD=0,LM=0;
#pragma unroll
        for (int q = 0; q < 4; ++q) {
            HD += sh[0][q][t]; HM += sh[1][q][t];
            WD += sh[2][q][t]; WM += sh[3][q][t];
            LD += sh[4][q][t]; LM += sh[5][q][t];
        }
        double term = LD/LM + WD/WM + HD/HM;
#pragma unroll
        for (int off = 32; off; off >>= 1) term += __shfl_xor(term, off);
        if ((tid & 63) == 0) sdbl[tid >> 6] = term;
    }
    __syncthreads();
    if (tid == 0) out[0] = (float)((sdbl[0] + sdbl[1] + sdbl[2]) * (1.0 / 192.0));
}

// ---------------- Path B fallback (small ws): R2 atomic scheme ----------------
__global__ __launch_bounds__(256) void slice_main_atomic(
    const float* __restrict__ vx,  const float* __restrict__ vy,
    const float* __restrict__ vz,  const float* __restrict__ p,
    const float* __restrict__ mask,
    const float* __restrict__ rvx, const float* __restrict__ rvy,
    const float* __restrict__ rvz, const float* __restrict__ rp,
    float* __restrict__ acc, int R)
{
    const int tid  = threadIdx.x;
    const int wv   = tid >> 6;
    const int lane = tid & 63;
    const bool act = lane < 48;
    const int hb   = lane << 2;
    float* __restrict__ racc = acc + (size_t)(blockIdx.x % R) * ACC_FLOATS;
    const int l  = blockIdx.x >> 2;
    const int w0 = (blockIdx.x & 3) * RPB;
    const int rowbase = l * GRID_N + w0 + wv * RPW;

    __shared__ float sD[4][192];
    __shared__ float sM[4][192];
    __shared__ float sRowD[RPB][49];
    __shared__ float sRowM[RPB][49];

    float cD0=0.f,cD1=0.f,cD2=0.f,cD3=0.f;
    float cM0=0.f,cM1=0.f,cM2=0.f,cM3=0.f;
#pragma unroll 4
    for (int r = 0; r < RPW; ++r) {
        const int row = rowbase + r;
        float d0=0.f,d1=0.f,d2=0.f,d3=0.f;
        float m0=0.f,m1=0.f,m2=0.f,m3=0.f;
        if (act) {
            const size_t base = (size_t)row * GRID_N + hb;
            float4 a, b;
            a = *(const float4*)(rvx + base); b = *(const float4*)(vx + base);
            d0 = a.x-b.x; d1 = a.y-b.y; d2 = a.z-b.z; d3 = a.w-b.w;
            a = *(const float4*)(rvy + base); b = *(const float4*)(vy + base);
            d0 += a.x-b.x; d1 += a.y-b.y; d2 += a.z-b.z; d3 += a.w-b.w;
            a = *(const float4*)(rvz + base); b = *(const float4*)(vz + base);
            d0 += a.x-b.x; d1 += a.y-b.y; d2 += a.z-b.z; d3 += a.w-b.w;
            a = *(const float4*)(rp  + base); b = *(const float4*)(p  + base);
            d0 += a.x-b.x; d1 += a.y-b.y; d2 += a.z-b.z; d3 += a.w-b.w;
            a = *(const float4*)(mask + base);
            m0 = a.x; m1 = a.y; m2 = a.z; m3 = a.w;
        }
        cD0 += d0; cD1 += d1; cD2 += d2; cD3 += d3;
        cM0 += m0; cM1 += m1; cM2 += m2; cM3 += m3;
        if (act) {
            sRowD[wv * RPW + r][lane] = (d0 + d1) + (d2 + d3);
            sRowM[wv * RPW + r][lane] = (m0 + m1) + (m2 + m3);
        }
    }
    if (act) {
        sD[wv][hb+0]=cD0; sD[wv][hb+1]=cD1; sD[wv][hb+2]=cD2; sD[wv][hb+3]=cD3;
        sM[wv][hb+0]=cM0; sM[wv][hb+1]=cM1; sM[wv][hb+2]=cM2; sM[wv][hb+3]=cM3;
    }
    __syncthreads();

    float d = 0.f, m = 0.f;
    if (tid < 192) {
        d = (sD[0][tid] + sD[1][tid]) + (sD[2][tid] + sD[3][tid]);
        m = (sM[0][tid] + sM[1][tid]) + (sM[2][tid] + sM[3][tid]);
        atomicAdd(&racc[tid],       d);
        atomicAdd(&racc[192 + tid], m);
    }
    if (tid < RPB) {
        float wd = 0.f, wm = 0.f;
#pragma unroll 8
        for (int i = 0; i < 48; ++i) { wd += sRowD[tid][i]; wm += sRowM[tid][i]; }
        atomicAdd(&racc[768 + w0 + tid], wd);
        atomicAdd(&racc[960 + w0 + tid], wm);
    }
    {
        float td = d, tm = m;
#pragma unroll
        for (int off = 32; off; off >>= 1) {
            td += __shfl_xor(td, off);
            tm += __shfl_xor(tm, off);
        }
        if (tid == 0 || tid == 64 || tid == 128 || tid == 192) {
            if (tid == 0) { } // only one atomic pair per block for l
        }
        __shared__ float sL[2][4];
        if (lane == 0) { sL[0][wv] = td; sL[1][wv] = tm; }
        __syncthreads();
        if (tid == 0) {
            atomicAdd(&racc[384 + l], (sL[0][0]+sL[0][1])+(sL[0][2]+sL[0][3]));
            atomicAdd(&racc[576 + l], (sL[1][0]+sL[1][1])+(sL[1][2]+sL[1][3]));
        }
    }
}

__global__ __launch_bounds__(192) void slice_final_atomic(
    const float* __restrict__ acc, float* __restrict__ out, int R)
{
    const int t = threadIdx.x;
    double hD=0, hM=0, lD=0, lM=0, wD=0, wM=0;
    for (int r = 0; r < R; ++r) {
        const float* a = acc + (size_t)r * ACC_FLOATS;
        hD += a[t];       hM += a[192 + t];
        lD += a[384 + t]; lM += a[576 + t];
        wD += a[768 + t]; wM += a[960 + t];
    }
    double term = lD / lM + wD / wM + hD / hM;
#pragma unroll
    for (int off = 32; off; off >>= 1) term += __shfl_xor(term, off);
    __shared__ double s[3];
    if ((t & 63) == 0) s[t >> 6] = term;
    __syncthreads();
    if (t == 0) out[0] = (float)((s[0] + s[1] + s[2]) * (1.0 / 192.0));
}

extern "C" void kernel_launch(void* const* d_in, const int* in_sizes, int n_in,
                              void* d_out, int out_size, void* d_ws, size_t ws_size,
                              hipStream_t stream)
{
    const float* vx   = (const float*)d_in[0];
    const float* vy   = (const float*)d_in[1];
    const float* vz   = (const float*)d_in[2];
    const float* p    = (const float*)d_in[3];
    const float* mask = (const float*)d_in[4];
    const float* rvx  = (const float*)d_in[5];
    const float* rvy  = (const float*)d_in[6];
    const float* rvz  = (const float*)d_in[7];
    const float* rp   = (const float*)d_in[8];

    if (ws_size >= STAGE_BYTES) {
        float* part = (float*)d_ws;
        slice_stage1<<<NBLK, 256, 0, stream>>>(vx, vy, vz, p, mask,
                                               rvx, rvy, rvz, rp, part);
        slice_stage2<<<1, 768, 0, stream>>>(part, (float*)d_out);
    } else {
        int R = (int)(ws_size / (ACC_FLOATS * sizeof(float)));
        if (R < 1)  R = 1;
        if (R > 64) R = 64;
        float* acc = (float*)d_ws;
        hipMemsetAsync(acc, 0, (size_t)R * ACC_FLOATS * sizeof(float), stream);
        slice_main_atomic<<<NBLK, 256, 0, stream>>>(vx, vy, vz, p, mask,
                                                    rvx, rvy, rvz, rp, acc, R);
        slice_final_atomic<<<1, 192, 0, stream>>>(acc, (float*)d_out, R);
    }
}

// Round 4
// 55.845 us; speedup vs baseline: 1.9155x; 1.9155x over previous
//
#include <hip/hip_runtime.h>

#define GRID_N 192
constexpr int NROWS = GRID_N * GRID_N;    // 36864 rows of 192 floats (h contiguous)
constexpr int RPB   = 24;                 // rows per block; block = one l, 24 consecutive w
constexpr int NBLK  = NROWS / RPB;        // 1536 blocks (8 per l-plane)
constexpr int RPW   = RPB / 4;            // 6 rows per wave

// Replicated accumulator: R copies of 1152 floats, replica = blockIdx % R.
//   [0..191]    hD   [192..383]  hM
//   [384..575]  lD   [576..767]  lM
//   [768..959]  wD   [960..1151] wM
constexpr int ACC_FLOATS = 1152;

#define LOAD_ROW(P, base) \
    P##0 = *(const float4*)(rvx + (base)); P##1 = *(const float4*)(vx + (base)); \
    P##2 = *(const float4*)(rvy + (base)); P##3 = *(const float4*)(vy + (base)); \
    P##4 = *(const float4*)(rvz + (base)); P##5 = *(const float4*)(vz + (base)); \
    P##6 = *(const float4*)(rp  + (base)); P##7 = *(const float4*)(p  + (base)); \
    P##8 = *(const float4*)(mask + (base));

__global__ __launch_bounds__(256) void slice_main(
    const float* __restrict__ vx,  const float* __restrict__ vy,
    const float* __restrict__ vz,  const float* __restrict__ p,
    const float* __restrict__ mask,
    const float* __restrict__ rvx, const float* __restrict__ rvy,
    const float* __restrict__ rvz, const float* __restrict__ rp,
    float* __restrict__ acc, int R)
{
    const int tid  = threadIdx.x;
    const int wv   = tid >> 6;
    const int lane = tid & 63;
    const bool act = lane < 48;           // 48 lanes x float4 = one 192-float row
    const int hb   = lane << 2;

    float* __restrict__ racc = acc + (size_t)(blockIdx.x % R) * ACC_FLOATS;

    const int l  = blockIdx.x >> 3;               // 8 blocks per l-plane
    const int w0 = (blockIdx.x & 7) * RPB;        // 24 consecutive w per block
    const int rowbase = l * GRID_N + w0 + wv * RPW;

    __shared__ float sD[4][192];
    __shared__ float sM[4][192];
    __shared__ float sRowD[RPB][49];              // [local w][lane], padded
    __shared__ float sRowM[RPB][49];
    __shared__ float sL[2][4];

    float cD0=0.f,cD1=0.f,cD2=0.f,cD3=0.f;
    float cM0=0.f,cM1=0.f,cM2=0.f,cM3=0.f;

    // process rows in pairs: 18 independent float4 loads in flight per iter
#pragma unroll 1
    for (int i = 0; i < RPW / 2; ++i) {
        const int rowA = rowbase + 2 * i;
        float4 A0,A1,A2,A3,A4,A5,A6,A7,A8;
        float4 B0,B1,B2,B3,B4,B5,B6,B7,B8;
        if (act) {
            const size_t baseA = (size_t)rowA * GRID_N + hb;
            const size_t baseB = baseA + GRID_N;
            LOAD_ROW(A, baseA)
            LOAD_ROW(B, baseB)

            float dA0 = (A0.x-A1.x) + (A2.x-A3.x) + (A4.x-A5.x) + (A6.x-A7.x);
            float dA1 = (A0.y-A1.y) + (A2.y-A3.y) + (A4.y-A5.y) + (A6.y-A7.y);
            float dA2 = (A0.z-A1.z) + (A2.z-A3.z) + (A4.z-A5.z) + (A6.z-A7.z);
            float dA3 = (A0.w-A1.w) + (A2.w-A3.w) + (A4.w-A5.w) + (A6.w-A7.w);
            float dB0 = (B0.x-B1.x) + (B2.x-B3.x) + (B4.x-B5.x) + (B6.x-B7.x);
            float dB1 = (B0.y-B1.y) + (B2.y-B3.y) + (B4.y-B5.y) + (B6.y-B7.y);
            float dB2 = (B0.z-B1.z) + (B2.z-B3.z) + (B4.z-B5.z) + (B6.z-B7.z);
            float dB3 = (B0.w-B1.w) + (B2.w-B3.w) + (B4.w-B5.w) + (B6.w-B7.w);

            cD0 += dA0 + dB0; cD1 += dA1 + dB1;
            cD2 += dA2 + dB2; cD3 += dA3 + dB3;
            cM0 += A8.x + B8.x; cM1 += A8.y + B8.y;
            cM2 += A8.z + B8.z; cM3 += A8.w + B8.w;

            const int lr = wv * RPW + 2 * i;
            sRowD[lr][lane]     = (dA0 + dA1) + (dA2 + dA3);
            sRowM[lr][lane]     = (A8.x + A8.y) + (A8.z + A8.w);
            sRowD[lr + 1][lane] = (dB0 + dB1) + (dB2 + dB3);
            sRowM[lr + 1][lane] = (B8.x + B8.y) + (B8.z + B8.w);
        }
    }

    if (act) {
        sD[wv][hb+0]=cD0; sD[wv][hb+1]=cD1; sD[wv][hb+2]=cD2; sD[wv][hb+3]=cD3;
        sM[wv][hb+0]=cM0; sM[wv][hb+1]=cM1; sM[wv][hb+2]=cM2; sM[wv][hb+3]=cM3;
    }
    __syncthreads();

    // h columns: one atomic per h per block into this block's replica
    float d = 0.f, m = 0.f;
    if (tid < 192) {
        d = (sD[0][tid] + sD[1][tid]) + (sD[2][tid] + sD[3][tid]);
        m = (sM[0][tid] + sM[1][tid]) + (sM[2][tid] + sM[3][tid]);
        atomicAdd(&racc[tid],       d);
        atomicAdd(&racc[192 + tid], m);
    }
    // w slots: reduce sRow[w][0..47], one atomic pair per local w
    if (tid < RPB) {
        float wd = 0.f, wm = 0.f;
#pragma unroll 8
        for (int i = 0; i < 48; ++i) { wd += sRowD[tid][i]; wm += sRowM[tid][i]; }
        atomicAdd(&racc[768 + w0 + tid], wd);
        atomicAdd(&racc[960 + w0 + tid], wm);
    }
    // l plane-partial = sum of this block's h-column totals
    {
        float td = d, tm = m;
#pragma unroll
        for (int off = 32; off; off >>= 1) {
            td += __shfl_xor(td, off);
            tm += __shfl_xor(tm, off);
        }
        if (lane == 0) { sL[0][wv] = td; sL[1][wv] = tm; }
    }
    __syncthreads();
    if (tid == 0) {
        atomicAdd(&racc[384 + l], (sL[0][0]+sL[0][1])+(sL[0][2]+sL[0][3]));
        atomicAdd(&racc[576 + l], (sL[1][0]+sL[1][1])+(sL[1][2]+sL[1][3]));
    }
}

__global__ __launch_bounds__(768) void slice_final(const float* __restrict__ acc,
                                                   float* __restrict__ out, int R)
{
    const int tid = threadIdx.x;
    const int t  = tid % 192;   // slice index
    const int g  = tid / 192;   // replica partition group 0..3

    float hD=0.f,hM=0.f,lD=0.f,lM=0.f,wD=0.f,wM=0.f;
    for (int r = g; r < R; r += 4) {
        const float* a = acc + (size_t)r * ACC_FLOATS;
        hD += a[t];       hM += a[192 + t];
        lD += a[384 + t]; lM += a[576 + t];
        wD += a[768 + t]; wM += a[960 + t];
    }

    __shared__ float sh[6][4][192];
    sh[0][g][t]=hD; sh[1][g][t]=hM; sh[2][g][t]=lD;
    sh[3][g][t]=lM; sh[4][g][t]=wD; sh[5][g][t]=wM;
    __syncthreads();

    __shared__ double sdbl[3];
    if (tid < 192) {
        double HD=0,HM=0,LD=0,LM=0,WD=0,WM=0;
#pragma unroll
        for (int q = 0; q < 4; ++q) {
            HD += sh[0][q][t]; HM += sh[1][q][t];
            LD += sh[2][q][t]; LM += sh[3][q][t];
            WD += sh[4][q][t]; WM += sh[5][q][t];
        }
        double term = LD/LM + WD/WM + HD/HM;
#pragma unroll
        for (int off = 32; off; off >>= 1) term += __shfl_xor(term, off);
        if ((tid & 63) == 0) sdbl[tid >> 6] = term;
    }
    __syncthreads();
    if (tid == 0) out[0] = (float)((sdbl[0] + sdbl[1] + sdbl[2]) * (1.0 / 192.0));
}

extern "C" void kernel_launch(void* const* d_in, const int* in_sizes, int n_in,
                              void* d_out, int out_size, void* d_ws, size_t ws_size,
                              hipStream_t stream)
{
    const float* vx   = (const float*)d_in[0];
    const float* vy   = (const float*)d_in[1];
    const float* vz   = (const float*)d_in[2];
    const float* p    = (const float*)d_in[3];
    const float* mask = (const float*)d_in[4];
    const float* rvx  = (const float*)d_in[5];
    const float* rvy  = (const float*)d_in[6];
    const float* rvz  = (const float*)d_in[7];
    const float* rp   = (const float*)d_in[8];

    int R = (int)(ws_size / (ACC_FLOATS * sizeof(float)));
    if (R < 1)  R = 1;
    if (R > 64) R = 64;

    float* acc = (float*)d_ws;
    hipMemsetAsync(acc, 0, (size_t)R * ACC_FLOATS * sizeof(float), stream);

    slice_main<<<NBLK, 256, 0, stream>>>(vx, vy, vz, p, mask,
                                         rvx, rvy, rvz, rp, acc, R);
    slice_final<<<1, 768, 0, stream>>>(acc, (float*)d_out, R);
}